// Round 1
// baseline (2933.478 us; speedup 1.0000x reference)
//
#include <hip/hip_runtime.h>

// Residual quantizer: N vectors (D=128), M=8 stages, K=256 codewords/stage.
// One thread per vector; res[] and rec[] live in VGPRs (~290 regs, 1 wave/SIMD,
// fine for a pure-VALU throughput kernel). Codebook rows are wave-uniform ->
// scalar loads (readfirstlane) so the inner loop is v_fmac_f32 v,s,v at 1 VALU/MAC.
// Distances replicate numpy's summation structure (pairwise-8 partials, fp32
// combine (rn - 2*dot) + cn) to keep argmin bit-compatible with the np reference.

constexpr int NV = 65536;
constexpr int DD = 128;
constexpr int MS = 8;
constexpr int KC = 256;

__global__ __launch_bounds__(256, 1)
void rq_kernel(const float* __restrict__ x,
               const float* __restrict__ cb,
               float* __restrict__ out)
{
    const int tid = threadIdx.x;
    const size_t n = (size_t)blockIdx.x * 256 + tid;

    __shared__ float cn[KC];

    float res[DD], rec[DD];
    {
        const float* xr = x + n * DD;
        #pragma unroll
        for (int d = 0; d < DD; d += 4) {
            float4 v = *(const float4*)(xr + d);
            res[d] = v.x; res[d+1] = v.y; res[d+2] = v.z; res[d+3] = v.w;
        }
    }
    #pragma unroll
    for (int d = 0; d < DD; ++d) rec[d] = 0.0f;

    float* out_recon = out;                                  // (N, D)
    float* out_codes = out + (size_t)NV * DD;                // (N, M, K)
    float* out_side  = out_codes + (size_t)NV * MS * KC;     // (M, N, D)

    for (int m = 0; m < MS; ++m) {
        const float* C = cb + (size_t)m * KC * DD;

        __syncthreads();   // previous stage's cn readers done
        {   // cn[tid] = ||C[tid]||^2, numpy pairwise-8 order
            const float* cr = C + tid * DD;
            float p[8];
            #pragma unroll
            for (int j = 0; j < 8; ++j) { float v = cr[j]; p[j] = v * v; }
            #pragma unroll
            for (int i = 8; i < DD; i += 8) {
                #pragma unroll
                for (int j = 0; j < 8; ++j) { float v = cr[i + j]; p[j] += v * v; }
            }
            cn[tid] = ((p[0]+p[1]) + (p[2]+p[3])) + ((p[4]+p[5]) + (p[6]+p[7]));
        }
        __syncthreads();

        float rn;
        {   // ||res||^2, same pairwise-8 order
            float p[8];
            #pragma unroll
            for (int j = 0; j < 8; ++j) p[j] = res[j] * res[j];
            #pragma unroll
            for (int i = 8; i < DD; i += 8) {
                #pragma unroll
                for (int j = 0; j < 8; ++j) p[j] += res[i + j] * res[i + j];
            }
            rn = ((p[0]+p[1]) + (p[2]+p[3])) + ((p[4]+p[5]) + (p[6]+p[7]));
        }

        float best = 3.402823466e38f;
        int bi = 0;
        #pragma unroll 2
        for (int k = 0; k < KC; ++k) {
            const int ku = __builtin_amdgcn_readfirstlane(k);   // force scalar (s_load) path
            const float* cr = C + ku * DD;
            float q[8];
            #pragma unroll
            for (int j = 0; j < 8; ++j) q[j] = res[j] * cr[j];
            #pragma unroll
            for (int i = 8; i < DD; i += 8) {
                #pragma unroll
                for (int j = 0; j < 8; ++j) q[j] += res[i + j] * cr[i + j];
            }
            float dot  = ((q[0]+q[1]) + (q[2]+q[3])) + ((q[4]+q[5]) + (q[6]+q[7]));
            float dist = (rn - 2.0f * dot) + cn[ku];            // same association as reference
            if (dist < best) { best = dist; bi = k; }           // strict <: first-min ties
        }

        // rec += c ; res = x - rec   (reference's exact association)
        {
            const float* cw = C + (size_t)bi * DD;
            const float* xr = x + n * DD;
            float* so = out_side + ((size_t)m * NV + n) * DD;
            #pragma unroll
            for (int d = 0; d < DD; d += 4) {
                float4 cv = *(const float4*)(cw + d);
                float4 xv = *(const float4*)(xr + d);
                rec[d]   += cv.x; rec[d+1] += cv.y; rec[d+2] += cv.z; rec[d+3] += cv.w;
                res[d]   = xv.x - rec[d];
                res[d+1] = xv.y - rec[d+1];
                res[d+2] = xv.z - rec[d+2];
                res[d+3] = xv.w - rec[d+3];
                float4 ov; ov.x = rec[d]; ov.y = rec[d+1]; ov.z = rec[d+2]; ov.w = rec[d+3];
                *(float4*)(so + d) = ov;
            }
        }

        // one-hot codes row (kernel writes the zeros too -> overlaps compute,
        // avoids a serial 536 MB memset dispatch)
        {
            float* crow = out_codes + n * (size_t)(MS * KC) + (size_t)m * KC;
            #pragma unroll
            for (int j = 0; j < KC; j += 4) {
                float4 v;
                v.x = (bi == j    ) ? 1.0f : 0.0f;
                v.y = (bi == j + 1) ? 1.0f : 0.0f;
                v.z = (bi == j + 2) ? 1.0f : 0.0f;
                v.w = (bi == j + 3) ? 1.0f : 0.0f;
                *(float4*)(crow + j) = v;
            }
        }
    }

    #pragma unroll
    for (int d = 0; d < DD; d += 4) {
        float4 v; v.x = rec[d]; v.y = rec[d+1]; v.z = rec[d+2]; v.w = rec[d+3];
        *(float4*)(out_recon + n * DD + d) = v;
    }
}

extern "C" void kernel_launch(void* const* d_in, const int* in_sizes, int n_in,
                              void* d_out, int out_size, void* d_ws, size_t ws_size,
                              hipStream_t stream)
{
    const float* x  = (const float*)d_in[0];
    const float* cb = (const float*)d_in[1];
    float* out = (float*)d_out;
    rq_kernel<<<dim3(NV / 256), dim3(256), 0, stream>>>(x, cb, out);
}

// Round 2
// 2784.532 us; speedup vs baseline: 1.0535x; 1.0535x over previous
//
#include <hip/hip_runtime.h>

// Residual quantizer: N=65536 vectors (D=128), M=8 stages, K=256 codewords.
// One thread per vector (structurally 1 wave/SIMD: occupancy is capped, all
// latency hiding must come from ILP). res[]/rec[] in VGPRs.
//
// R1->R2: codebook rows moved from scalar s_load chains (L2 latency-serialized,
// VALUBusy 11.5%) to LDS chunks; k-loop reads are wave-uniform ds_read_b128
// broadcasts which the compiler pipelines under lgkmcnt.
//
// Numerics: distances replicate numpy's pairwise-8 summation (8 accumulators,
// 16 sequential adds each, ((p0+p1)+(p2+p3))+((p4+p5)+(p6+p7)) combine) and the
// reference association (rn - 2*dot) + cn, strict < argmin. R1 measured
// absmax 0.0 (bitwise match) -- do not alter any FP order.

constexpr int NV = 65536;
constexpr int DD = 128;
constexpr int MS = 8;
constexpr int KC = 256;
constexpr int CH = 112;   // codebook rows per LDS chunk: 112*128*4 = 57344 B

__global__ __launch_bounds__(256, 1)
void rq_kernel(const float* __restrict__ x,
               const float* __restrict__ cb,
               float* __restrict__ out)
{
    const int tid = threadIdx.x;
    const size_t n = (size_t)blockIdx.x * 256 + tid;

    __shared__ float sC[CH * DD];   // 57344 B
    __shared__ float cn_s[CH];      // 448 B

    float res[DD], rec[DD];
    {
        const float* xr = x + n * DD;
        #pragma unroll
        for (int d = 0; d < DD; d += 4) {
            float4 v = *(const float4*)(xr + d);
            res[d] = v.x; res[d+1] = v.y; res[d+2] = v.z; res[d+3] = v.w;
        }
    }
    #pragma unroll
    for (int d = 0; d < DD; ++d) rec[d] = 0.0f;

    float* out_recon = out;                                  // (N, D)
    float* out_codes = out + (size_t)NV * DD;                // (N, M, K)
    float* out_side  = out_codes + (size_t)NV * MS * KC;     // (M, N, D)

    for (int m = 0; m < MS; ++m) {
        const float* C = cb + (size_t)m * KC * DD;

        float rn;
        {   // ||res||^2, numpy pairwise-8 order
            float p[8];
            #pragma unroll
            for (int j = 0; j < 8; ++j) p[j] = res[j] * res[j];
            #pragma unroll
            for (int i = 8; i < DD; i += 8) {
                #pragma unroll
                for (int j = 0; j < 8; ++j) p[j] += res[i + j] * res[i + j];
            }
            rn = ((p[0]+p[1]) + (p[2]+p[3])) + ((p[4]+p[5]) + (p[6]+p[7]));
        }

        float best = 3.402823466e38f;
        int bi = 0;

        for (int base = 0; base < KC; base += CH) {
            const int rows = (KC - base) < CH ? (KC - base) : CH;

            __syncthreads();   // prior chunk's readers done before overwrite

            // stage chunk: coalesced float4 global->LDS
            {
                const float4* g4 = (const float4*)(C + (size_t)base * DD);
                float4* s4 = (float4*)sC;
                const int nf4 = rows * (DD / 4);
                for (int i = tid; i < nf4; i += 256) s4[i] = g4[i];
            }
            // cn for this chunk (from global; values bitwise-same as R1)
            if (tid < rows) {
                const float* cr = C + (size_t)(base + tid) * DD;
                float p[8];
                #pragma unroll
                for (int j = 0; j < 8; ++j) { float v = cr[j]; p[j] = v * v; }
                #pragma unroll
                for (int i = 8; i < DD; i += 8) {
                    #pragma unroll
                    for (int j = 0; j < 8; ++j) { float v = cr[i + j]; p[j] += v * v; }
                }
                cn_s[tid] = ((p[0]+p[1]) + (p[2]+p[3])) + ((p[4]+p[5]) + (p[6]+p[7]));
            }
            __syncthreads();

            #pragma unroll 2
            for (int kk = 0; kk < rows; ++kk) {
                const float4* cr4 = (const float4*)(sC + kk * DD);
                float q[8];
                {
                    float4 a = cr4[0], b = cr4[1];
                    q[0] = res[0] * a.x; q[1] = res[1] * a.y;
                    q[2] = res[2] * a.z; q[3] = res[3] * a.w;
                    q[4] = res[4] * b.x; q[5] = res[5] * b.y;
                    q[6] = res[6] * b.z; q[7] = res[7] * b.w;
                }
                #pragma unroll
                for (int i = 8; i < DD; i += 8) {
                    float4 a = cr4[i / 4], b = cr4[i / 4 + 1];
                    q[0] += res[i]     * a.x; q[1] += res[i + 1] * a.y;
                    q[2] += res[i + 2] * a.z; q[3] += res[i + 3] * a.w;
                    q[4] += res[i + 4] * b.x; q[5] += res[i + 5] * b.y;
                    q[6] += res[i + 6] * b.z; q[7] += res[i + 7] * b.w;
                }
                float dot  = ((q[0]+q[1]) + (q[2]+q[3])) + ((q[4]+q[5]) + (q[6]+q[7]));
                float dist = (rn - 2.0f * dot) + cn_s[kk];     // reference association
                if (dist < best) { best = dist; bi = base + kk; }  // strict <
            }
        }

        // rec += c ; res = x - rec   (reference's exact association)
        {
            const float* cw = C + (size_t)bi * DD;
            const float* xr = x + n * DD;
            float* so = out_side + ((size_t)m * NV + n) * DD;
            #pragma unroll
            for (int d = 0; d < DD; d += 4) {
                float4 cv = *(const float4*)(cw + d);
                float4 xv = *(const float4*)(xr + d);
                rec[d]   += cv.x; rec[d+1] += cv.y; rec[d+2] += cv.z; rec[d+3] += cv.w;
                res[d]   = xv.x - rec[d];
                res[d+1] = xv.y - rec[d+1];
                res[d+2] = xv.z - rec[d+2];
                res[d+3] = xv.w - rec[d+3];
                float4 ov; ov.x = rec[d]; ov.y = rec[d+1]; ov.z = rec[d+2]; ov.w = rec[d+3];
                *(float4*)(so + d) = ov;
            }
        }

        // one-hot codes row (zeros written here too -> overlaps compute)
        {
            float* crow = out_codes + n * (size_t)(MS * KC) + (size_t)m * KC;
            #pragma unroll
            for (int j = 0; j < KC; j += 4) {
                float4 v;
                v.x = (bi == j    ) ? 1.0f : 0.0f;
                v.y = (bi == j + 1) ? 1.0f : 0.0f;
                v.z = (bi == j + 2) ? 1.0f : 0.0f;
                v.w = (bi == j + 3) ? 1.0f : 0.0f;
                *(float4*)(crow + j) = v;
            }
        }
    }

    #pragma unroll
    for (int d = 0; d < DD; d += 4) {
        float4 v; v.x = rec[d]; v.y = rec[d+1]; v.z = rec[d+2]; v.w = rec[d+3];
        *(float4*)(out_recon + n * DD + d) = v;
    }
}

extern "C" void kernel_launch(void* const* d_in, const int* in_sizes, int n_in,
                              void* d_out, int out_size, void* d_ws, size_t ws_size,
                              hipStream_t stream)
{
    const float* x  = (const float*)d_in[0];
    const float* cb = (const float*)d_in[1];
    float* out = (float*)d_out;
    rq_kernel<<<dim3(NV / 256), dim3(256), 0, stream>>>(x, cb, out);
}